// Round 7
// baseline (148.122 us; speedup 1.0000x reference)
//
#include <hip/hip_runtime.h>
#include <hip/hip_bf16.h>

#define N_B 2
#define L_Q 2048
#define S_K 2048
#define N_H 8
#define D_H 64
#define HD  512   /* N_H * D_H */
#define KVB 64
#define NT  32    /* kv tiles total */
#define RS  72    /* pl row stride in bf16 elems */
#define PQT ((size_t)N_B * L_Q * N_H)   /* 32768 q-rows */
#define LOG2E 1.4426950408889634f

typedef __attribute__((ext_vector_type(8))) short bf16x8;
typedef __attribute__((ext_vector_type(4))) short short4v;
typedef __attribute__((ext_vector_type(4))) float f32x4;

__device__ __forceinline__ short f2bf(float f) {
  union { float f; unsigned u; } v; v.f = f;
  return (short)((v.u + 0x7FFFu + ((v.u >> 16) & 1u)) >> 16);
}
__device__ __forceinline__ float bf2f(short s) {
  union { unsigned u; float f; } w; w.u = ((unsigned)(unsigned short)s) << 16;
  return w.f;
}
__device__ __forceinline__ bf16x8 pack8(float4 a, float4 b) {
  bf16x8 t;
  t[0]=f2bf(a.x); t[1]=f2bf(a.y); t[2]=f2bf(a.z); t[3]=f2bf(a.w);
  t[4]=f2bf(b.x); t[5]=f2bf(b.y); t[6]=f2bf(b.z); t[7]=f2bf(b.w);
  return t;
}

// ---------------- pre-convert: fp32 K,V -> bf16 ws; kv_mask -> bitfield ----
__global__ __launch_bounds__(256)
void preconv_kernel(const float* __restrict__ K, const float* __restrict__ V,
                    const int* __restrict__ kvm,
                    short* __restrict__ kws, short* __restrict__ vws,
                    unsigned long long* __restrict__ mws) {
  const size_t i = (size_t)blockIdx.x * 256 + threadIdx.x;
  const float4* kp = (const float4*)K + i * 2;
  float4 a = kp[0], b = kp[1];
  *(bf16x8*)(kws + i * 8) = pack8(a, b);
  const float4* vp = (const float4*)V + i * 2;
  float4 c = vp[0], d = vp[1];
  *(bf16x8*)(vws + i * 8) = pack8(c, d);
  if (blockIdx.x == 0 && threadIdx.x < (N_B * S_K / 64)) {
    const int* src = kvm + threadIdx.x * 64;
    unsigned long long m = 0;
    #pragma unroll 8
    for (int bb = 0; bb < 64; ++bb) m |= (src[bb] ? 1ull : 0ull) << bb;
    mws[threadIdx.x] = m;
  }
}

// ---------------- main: 256 threads (4 waves x 16 q-rows), dbuf LDS --------
// split==2: each block does half the KV tiles, writes raw partials to ws.
// split==1: full KV range, writes normalized output directly.
__global__ __launch_bounds__(256, 3)
void attn_fwd_v3(const float* __restrict__ Q, const short* __restrict__ Kb,
                 const short* __restrict__ Vb,
                 const unsigned long long* __restrict__ mbits,
                 float* __restrict__ Out,
                 float* __restrict__ Ow, float* __restrict__ Mw,
                 float* __restrict__ Lw, int split) {
  // kt: 2 bufs x [64 rows x 128B], XOR-swizzled (byte ^= (row&7)<<4)
  // vt: 2 bufs x subtiled [k/4][d/16][4][16] for ds_read_b64_tr_b16
  __shared__ __align__(128) short kt[2 * 4096];
  __shared__ __align__(128) short vt[2 * 4096];
  __shared__ __align__(16)  short pl[4][16 * RS];

  const int tid  = threadIdx.x;
  const int wid  = tid >> 6;
  const int lane = tid & 63;
  const int l16  = lane & 15;
  const int lg   = lane >> 4;

  // bijective XCD swizzle (gridDim %8==0): same (n,h) clusters on one XCD
  const int per_xcd = gridDim.x >> 3;
  const int logical = (blockIdx.x & 7) * per_xcd + (blockIdx.x >> 3);
  int nh, sp, qb;
  if (split == 2) { nh = logical >> 6; sp = (logical >> 5) & 1; qb = logical & 31; }
  else            { nh = logical >> 5; sp = 0;                  qb = logical & 31; }
  const int n  = nh >> 3;
  const int h  = nh & 7;
  const int q0 = qb * 64 + wid * 16;
  const int tps = (split == 2) ? (NT / 2) : NT;
  const int t0 = sp * tps, t1 = t0 + tps;

  const float* Qn = Q + ((size_t)n * L_Q) * HD + h * D_H;
  const char*  Kn = (const char*)(Kb + ((size_t)n * S_K) * HD + h * D_H); // row stride 1024B
  const char*  Vn = (const char*)(Vb + ((size_t)n * S_K) * HD + h * D_H);

  // ---- per-lane staging offsets (2 chunks of 1024B per wave per tensor) ----
  int koffb[2], voffb[2];
  #pragma unroll
  for (int i = 0; i < 2; ++i) {
    const int p   = (wid * 2 + i) * 1024 + lane * 16;   // phys byte in 8KB tile
    const int row = p >> 7;
    const int cb  = (p & 127) ^ ((row & 7) << 4);       // inverse of read swizzle
    koffb[i] = row * 1024 + cb;
    const int k  = ((p >> 9) << 2) | ((p >> 5) & 3);    // subtile decode
    const int d  = (((p >> 7) & 3) << 4) | ((p >> 1) & 15);
    voffb[i] = k * 1024 + d * 2;
  }

  // ---- Q fragments (A-layout: row l16, k = lg*8+i, +32 per chunk), x0.125 --
  bf16x8 qf[2];
  {
    const float* qp = Qn + (size_t)(q0 + l16) * HD + lg * 8;
    #pragma unroll
    for (int c = 0; c < 2; ++c) {
      float4 a = *(const float4*)(qp + c * 32);
      float4 b = *(const float4*)(qp + c * 32 + 4);
      float4 as, bs;
      as.x=a.x*0.125f; as.y=a.y*0.125f; as.z=a.z*0.125f; as.w=a.w*0.125f;
      bs.x=b.x*0.125f; bs.y=b.y*0.125f; bs.z=b.z*0.125f; bs.w=b.w*0.125f;
      qf[c] = pack8(as, bs);
    }
  }

  // per-lane K-frag read addrs (bytes within one 8KB buffer), swizzled
  const int swz    = (l16 & 7) << 4;
  const int kaddrA = l16 * 128 + ((lg * 16) ^ swz);
  const int kaddrB = l16 * 128 + ((64 + lg * 16) ^ swz);
  const int vlane  = lg * 1024 + l16 * 8;   // tr-read per-lane base
  const unsigned vt0 = (unsigned)(size_t)(__attribute__((address_space(3))) char*)((char*)&vt[0]);

  f32x4 o[4];
  #pragma unroll
  for (int g = 0; g < 4; ++g) o[g] = (f32x4){0.f, 0.f, 0.f, 0.f};
  float m_run[4], l_run[4];
  #pragma unroll
  for (int r = 0; r < 4; ++r) { m_run[r] = -3e38f; l_run[r] = 0.f; }

  short* pw = pl[wid];

  #define ISSUE(t_) do {                                                          \
    const int bs_ = ((t_) & 1) * 8192;                                            \
    const char* ks_ = Kn + (size_t)(t_) * 65536;                                  \
    const char* vs_ = Vn + (size_t)(t_) * 65536;                                  \
    _Pragma("unroll")                                                             \
    for (int i_ = 0; i_ < 2; ++i_) {                                              \
      __builtin_amdgcn_global_load_lds(                                           \
        (const __attribute__((address_space(1))) void*)(ks_ + koffb[i_]),         \
        (__attribute__((address_space(3))) void*)((char*)kt + bs_ + (wid*2+i_)*1024), \
        16, 0, 0);                                                                \
      __builtin_amdgcn_global_load_lds(                                           \
        (const __attribute__((address_space(1))) void*)(vs_ + voffb[i_]),         \
        (__attribute__((address_space(3))) void*)((char*)vt + bs_ + (wid*2+i_)*1024), \
        16, 0, 0);                                                                \
    }                                                                             \
  } while (0)

  ISSUE(t0);

  for (int t = t0; t < t1; ++t) {
    __syncthreads();            // drains vmcnt -> buf[t&1] staged; prev reads done
    if (t + 1 < t1) ISSUE(t + 1);
    const int bo = (t & 1) * 8192;

    // ---- QK^T ----
    f32x4 sc[4];
    #pragma unroll
    for (int g = 0; g < 4; ++g) {
      bf16x8 kb0 = *(const bf16x8*)((const char*)kt + bo + g * 2048 + kaddrA);
      bf16x8 kb1 = *(const bf16x8*)((const char*)kt + bo + g * 2048 + kaddrB);
      f32x4 z = (f32x4){0.f, 0.f, 0.f, 0.f};
      z = __builtin_amdgcn_mfma_f32_16x16x32_bf16(qf[0], kb0, z, 0, 0, 0);
      z = __builtin_amdgcn_mfma_f32_16x16x32_bf16(qf[1], kb1, z, 0, 0, 0);
      sc[g] = z;
    }

    // ---- kv mask (bitfield, wave-uniform load) ----
    const unsigned long long mb = mbits[n * NT + t];
    #pragma unroll
    for (int g = 0; g < 4; ++g) {
      if (!((mb >> (g * 16 + l16)) & 1ull)) {
        #pragma unroll
        for (int r = 0; r < 4; ++r) sc[g][r] = -3e38f;
      }
    }

    // ---- online softmax ----
    float mt[4];
    #pragma unroll
    for (int r = 0; r < 4; ++r) {
      float v = fmaxf(fmaxf(sc[0][r], sc[1][r]), fmaxf(sc[2][r], sc[3][r]));
      v = fmaxf(v, __shfl_xor(v, 1));
      v = fmaxf(v, __shfl_xor(v, 2));
      v = fmaxf(v, __shfl_xor(v, 4));
      v = fmaxf(v, __shfl_xor(v, 8));
      mt[r] = v;
    }
    float alpha[4];
    #pragma unroll
    for (int r = 0; r < 4; ++r) {
      float mn = fmaxf(m_run[r], mt[r]);
      alpha[r] = __builtin_amdgcn_exp2f((m_run[r] - mn) * LOG2E);
      m_run[r] = mn;
    }
    float rsum[4] = {0.f, 0.f, 0.f, 0.f};
    short pb[4][4];
    #pragma unroll
    for (int g = 0; g < 4; ++g) {
      #pragma unroll
      for (int r = 0; r < 4; ++r) {
        float p = __builtin_amdgcn_exp2f((sc[g][r] - m_run[r]) * LOG2E);
        short s = f2bf(p);
        pb[g][r] = s;
        rsum[r] += bf2f(s);
      }
    }
    #pragma unroll
    for (int r = 0; r < 4; ++r) {
      float v = rsum[r];
      v += __shfl_xor(v, 1);
      v += __shfl_xor(v, 2);
      v += __shfl_xor(v, 4);
      v += __shfl_xor(v, 8);
      l_run[r] = l_run[r] * alpha[r] + v;
    }
    #pragma unroll
    for (int g = 0; g < 4; ++g) {
      f32x4 tv = o[g];
      #pragma unroll
      for (int r = 0; r < 4; ++r) tv[r] *= alpha[r];
      o[g] = tv;
    }

    // ---- P: D-layout -> A-layout via per-wave LDS buffer (no barrier) ----
    #pragma unroll
    for (int g = 0; g < 4; ++g)
      #pragma unroll
      for (int r = 0; r < 4; ++r)
        pw[(lg * 4 + r) * RS + g * 16 + l16] = pb[g][r];

    bf16x8 pa0 = *(const bf16x8*)&pw[l16 * RS + lg * 8];
    bf16x8 pa1 = *(const bf16x8*)&pw[l16 * RS + 32 + lg * 8];

    // ---- V B-fragments via HW transpose read ----
    const unsigned va = vt0 + (unsigned)(bo + vlane);
    #define TRRD(dst, off) asm volatile("ds_read_b64_tr_b16 %0, %1 offset:" off \
                                        : "=v"(dst) : "v"(va))
    short4v w0la, w0lb, w0ha, w0hb, w1la, w1lb, w1ha, w1hb;
    short4v w2la, w2lb, w2ha, w2hb, w3la, w3lb, w3ha, w3hb;
    TRRD(w0la, "0");   TRRD(w0lb, "512"); TRRD(w0ha, "4096"); TRRD(w0hb, "4608");
    TRRD(w1la, "128"); TRRD(w1lb, "640"); TRRD(w1ha, "4224"); TRRD(w1hb, "4736");
    TRRD(w2la, "256"); TRRD(w2lb, "768"); TRRD(w2ha, "4352"); TRRD(w2hb, "4864");
    TRRD(w3la, "384"); TRRD(w3lb, "896"); TRRD(w3ha, "4480"); TRRD(w3hb, "4992");
    asm volatile("s_waitcnt lgkmcnt(0)" ::: "memory");
    __builtin_amdgcn_sched_barrier(0);

    bf16x8 v0l = __builtin_shufflevector(w0la, w0lb, 0,1,2,3,4,5,6,7);
    bf16x8 v0h = __builtin_shufflevector(w0ha, w0hb, 0,1,2,3,4,5,6,7);
    bf16x8 v1l = __builtin_shufflevector(w1la, w1lb, 0,1,2,3,4,5,6,7);
    bf16x8 v1h = __builtin_shufflevector(w1ha, w1hb, 0,1,2,3,4,5,6,7);
    bf16x8 v2l = __builtin_shufflevector(w2la, w2lb, 0,1,2,3,4,5,6,7);
    bf16x8 v2h = __builtin_shufflevector(w2ha, w2hb, 0,1,2,3,4,5,6,7);
    bf16x8 v3l = __builtin_shufflevector(w3la, w3lb, 0,1,2,3,4,5,6,7);
    bf16x8 v3h = __builtin_shufflevector(w3ha, w3hb, 0,1,2,3,4,5,6,7);

    o[0] = __builtin_amdgcn_mfma_f32_16x16x32_bf16(pa0, v0l, o[0], 0, 0, 0);
    o[0] = __builtin_amdgcn_mfma_f32_16x16x32_bf16(pa1, v0h, o[0], 0, 0, 0);
    o[1] = __builtin_amdgcn_mfma_f32_16x16x32_bf16(pa0, v1l, o[1], 0, 0, 0);
    o[1] = __builtin_amdgcn_mfma_f32_16x16x32_bf16(pa1, v1h, o[1], 0, 0, 0);
    o[2] = __builtin_amdgcn_mfma_f32_16x16x32_bf16(pa0, v2l, o[2], 0, 0, 0);
    o[2] = __builtin_amdgcn_mfma_f32_16x16x32_bf16(pa1, v2h, o[2], 0, 0, 0);
    o[3] = __builtin_amdgcn_mfma_f32_16x16x32_bf16(pa0, v3l, o[3], 0, 0, 0);
    o[3] = __builtin_amdgcn_mfma_f32_16x16x32_bf16(pa1, v3h, o[3], 0, 0, 0);
  }

  // ---- epilogue ----
  if (split == 2) {
    #pragma unroll
    for (int r = 0; r < 4; ++r) {
      const size_t row = ((size_t)n * L_Q + q0 + lg * 4 + r) * N_H + h;
      const size_t ob  = ((size_t)sp * PQT + row) * D_H;
      #pragma unroll
      for (int gd = 0; gd < 4; ++gd)
        Ow[ob + gd * 16 + l16] = o[gd][r];
      if (l16 == 0) { Mw[sp * PQT + row] = m_run[r]; Lw[sp * PQT + row] = l_run[r]; }
    }
  } else {
    float* op = Out + ((size_t)n * L_Q + q0) * HD + h * D_H;
    float inv[4];
    #pragma unroll
    for (int r = 0; r < 4; ++r) inv[r] = 1.0f / l_run[r];
    #pragma unroll
    for (int gd = 0; gd < 4; ++gd)
      #pragma unroll
      for (int r = 0; r < 4; ++r)
        op[(size_t)(lg * 4 + r) * HD + gd * 16 + l16] = o[gd][r] * inv[r];
  }
}

// ---------------- combine: merge the 2 KV-split partials ------------------
__global__ __launch_bounds__(256)
void combine_kernel(const float* __restrict__ Ow, const float* __restrict__ Mw,
                    const float* __restrict__ Lw, float* __restrict__ Out) {
  const int gid = blockIdx.x * 256 + threadIdx.x;   // 524288 threads
  const size_t rid = (size_t)(gid >> 4);            // q-row id in [n][q][h] order
  const int d0 = (gid & 15) << 2;
  float m0 = Mw[rid],       l0 = Lw[rid];
  float m1 = Mw[PQT + rid], l1 = Lw[PQT + rid];
  float M  = fmaxf(m0, m1);
  float w0 = __builtin_amdgcn_exp2f((m0 - M) * LOG2E);
  float w1 = __builtin_amdgcn_exp2f((m1 - M) * LOG2E);
  float inv = 1.0f / (l0 * w0 + l1 * w1);
  const float4 o0 = *(const float4*)(Ow + rid * D_H + d0);
  const float4 o1 = *(const float4*)(Ow + (PQT + rid) * D_H + d0);
  float4 r;
  r.x = (o0.x * w0 + o1.x * w1) * inv;
  r.y = (o0.y * w0 + o1.y * w1) * inv;
  r.z = (o0.z * w0 + o1.z * w1) * inv;
  r.w = (o0.w * w0 + o1.w * w1) * inv;
  *(float4*)(Out + rid * D_H + d0) = r;
}

// ---------------- fallback (Round-3 kernel, proven, ws-free) ---------------
__global__ __launch_bounds__(256, 2)
void attn_fwd_kernel(const float* __restrict__ Q, const float* __restrict__ K,
                     const float* __restrict__ V,
                     const int* __restrict__ q_mask,
                     const int* __restrict__ kv_mask,
                     float* __restrict__ Out) {
  __shared__ __align__(16) short kts[KVB * RS];
  __shared__ __align__(16) short vts[D_H * RS];
  __shared__ __align__(16) short pls[4][16 * RS];
  const int tid = threadIdx.x, wid = tid >> 6, lane = tid & 63;
  const int l16 = lane & 15, lg = lane >> 4;
  const int bid = blockIdx.x, nh = bid >> 5, qb = bid & 31;
  const int n = nh >> 3, h = nh & 7, q0 = qb * 64 + wid * 16;
  const float* Qb = Q + ((size_t)n * L_Q) * HD + h * D_H;
  const float* Kb = K + ((size_t)n * S_K) * HD + h * D_H;
  const float* Vb = V + ((size_t)n * S_K) * HD + h * D_H;
  const int* km = kv_mask + (size_t)n * S_K;
  (void)q_mask;
  bf16x8 qf[2];
  {
    const float* qp = Qb + (size_t)(q0 + l16) * HD + lg * 8;
    #pragma unroll
    for (int c = 0; c < 2; ++c) {
      float4 a = *(const float4*)(qp + c * 32);
      float4 b = *(const float4*)(qp + c * 32 + 4);
      float4 as, bs;
      as.x=a.x*0.125f; as.y=a.y*0.125f; as.z=a.z*0.125f; as.w=a.w*0.125f;
      bs.x=b.x*0.125f; bs.y=b.y*0.125f; bs.z=b.z*0.125f; bs.w=b.w*0.125f;
      qf[c] = pack8(as, bs);
    }
  }
  f32x4 o[4];
  #pragma unroll
  for (int g = 0; g < 4; ++g) o[g] = (f32x4){0.f, 0.f, 0.f, 0.f};
  float m_run[4], l_run[4];
  #pragma unroll
  for (int r = 0; r < 4; ++r) { m_run[r] = -3e38f; l_run[r] = 0.f; }
  for (int s0 = 0; s0 < S_K; s0 += KVB) {
    __syncthreads();
    {
      const int cid = tid << 1, row = cid >> 3, c0 = cid & 7;
      const float* kp = Kb + (size_t)(s0 + row) * HD + c0 * 8;
      float4 f0 = *(const float4*)(kp), f1 = *(const float4*)(kp + 4);
      float4 f2 = *(const float4*)(kp + 8), f3 = *(const float4*)(kp + 12);
      *(bf16x8*)&kts[row * RS + c0 * 8]     = pack8(f0, f1);
      *(bf16x8*)&kts[row * RS + c0 * 8 + 8] = pack8(f2, f3);
    }
    {
      const int kv = tid >> 2, dc = tid & 3;
      const float* vp = Vb + (size_t)(s0 + kv) * HD + dc * 16;
      float4 f0 = *(const float4*)(vp), f1 = *(const float4*)(vp + 4);
      float4 f2 = *(const float4*)(vp + 8), f3 = *(const float4*)(vp + 12);
      float tv[16] = { f0.x,f0.y,f0.z,f0.w, f1.x,f1.y,f1.z,f1.w,
                       f2.x,f2.y,f2.z,f2.w, f3.x,f3.y,f3.z,f3.w };
      short* dst = &vts[(dc * 16) * RS + kv];
      #pragma unroll
      for (int j = 0; j < 16; ++j) dst[j * RS] = f2bf(tv[j]);
    }
    __syncthreads();
    f32x4 sc[4];
    #pragma unroll
    for (int g = 0; g < 4; ++g) {
      bf16x8 kb0 = *(const bf16x8*)&kts[(g*16 + l16) * RS + lg * 8];
      bf16x8 kb1 = *(const bf16x8*)&kts[(g*16 + l16) * RS + 32 + lg * 8];
      f32x4 z = (f32x4){0.f, 0.f, 0.f, 0.f};
      z = __builtin_amdgcn_mfma_f32_16x16x32_bf16(qf[0], kb0, z, 0, 0, 0);
      z = __builtin_amdgcn_mfma_f32_16x16x32_bf16(qf[1], kb1, z, 0, 0, 0);
      sc[g] = z;
    }
    #pragma unroll
    for (int g = 0; g < 4; ++g) {
      float b = km[s0 + g*16 + l16] ? 0.f : -3e38f;
      #pragma unroll
      for (int r = 0; r < 4; ++r) sc[g][r] += b;
    }
    float mt[4];
    #pragma unroll
    for (int r = 0; r < 4; ++r) {
      float v = fmaxf(fmaxf(sc[0][r], sc[1][r]), fmaxf(sc[2][r], sc[3][r]));
      v = fmaxf(v, __shfl_xor(v, 1)); v = fmaxf(v, __shfl_xor(v, 2));
      v = fmaxf(v, __shfl_xor(v, 4)); v = fmaxf(v, __shfl_xor(v, 8));
      mt[r] = v;
    }
    float alpha[4];
    #pragma unroll
    for (int r = 0; r < 4; ++r) {
      float mn = fmaxf(m_run[r], mt[r]);
      alpha[r] = __builtin_amdgcn_exp2f((m_run[r] - mn) * LOG2E);
      m_run[r] = mn;
    }
    float rsum[4] = {0.f, 0.f, 0.f, 0.f};
    short pb[4][4];
    #pragma unroll
    for (int g = 0; g < 4; ++g)
      #pragma unroll
      for (int r = 0; r < 4; ++r) {
        float p = __builtin_amdgcn_exp2f((sc[g][r] - m_run[r]) * LOG2E);
        short s = f2bf(p); pb[g][r] = s; rsum[r] += bf2f(s);
      }
    #pragma unroll
    for (int r = 0; r < 4; ++r) {
      float v = rsum[r];
      v += __shfl_xor(v, 1); v += __shfl_xor(v, 2);
      v += __shfl_xor(v, 4); v += __shfl_xor(v, 8);
      l_run[r] = l_run[r] * alpha[r] + v;
    }
    #pragma unroll
    for (int g = 0; g < 4; ++g)
      #pragma unroll
      for (int r = 0; r < 4; ++r) o[g][r] *= alpha[r];
    short* pwf = pls[wid];
    #pragma unroll
    for (int g = 0; g < 4; ++g)
      #pragma unroll
      for (int r = 0; r < 4; ++r)
        pwf[(lg*4 + r) * RS + g*16 + l16] = pb[g][r];
    __syncthreads();
    bf16x8 pa0 = *(const bf16x8*)&pwf[l16 * RS + lg * 8];
    bf16x8 pa1 = *(const bf16x8*)&pwf[l16 * RS + 32 + lg * 8];
    #pragma unroll
    for (int gd = 0; gd < 4; ++gd) {
      bf16x8 vb0 = *(const bf16x8*)&vts[(gd*16 + l16) * RS + lg * 8];
      bf16x8 vb1 = *(const bf16x8*)&vts[(gd*16 + l16) * RS + 32 + lg * 8];
      o[gd] = __builtin_amdgcn_mfma_f32_16x16x32_bf16(pa0, vb0, o[gd], 0, 0, 0);
      o[gd] = __builtin_amdgcn_mfma_f32_16x16x32_bf16(pa1, vb1, o[gd], 0, 0, 0);
    }
  }
  float* op = Out + ((size_t)n * L_Q + q0) * HD + h * D_H;
  float inv[4];
  #pragma unroll
  for (int r = 0; r < 4; ++r) inv[r] = 1.0f / l_run[r];
  #pragma unroll
  for (int gd = 0; gd < 4; ++gd)
    #pragma unroll
    for (int r = 0; r < 4; ++r)
      op[(size_t)(lg*4 + r) * HD + gd*16 + l16] = o[gd][r] * inv[r];
}

extern "C" void kernel_launch(void* const* d_in, const int* in_sizes, int n_in,
                              void* d_out, int out_size, void* d_ws, size_t ws_size,
                              hipStream_t stream) {
  const float* Q = (const float*)d_in[0];
  const float* K = (const float*)d_in[1];
  const float* V = (const float*)d_in[2];
  const int* qm = (const int*)d_in[3];
  const int* km = (const int*)d_in[4];
  float* Out = (float*)d_out;
  (void)in_sizes; (void)n_in; (void)out_size;

  const size_t kbytes  = (size_t)N_B * S_K * HD * 2;            // 4 MiB
  const size_t need1   = 2 * kbytes + 1024;                      // preconv tier
  const size_t owbytes = 2 * PQT * D_H * sizeof(float);          // 16.78 MB
  const size_t mlbytes = 2 * PQT * sizeof(float);                // 0.26 MB each
  const size_t need2   = need1 + owbytes + 2 * mlbytes;          // ~25.7 MB

  if (ws_size >= need1) {
    short* kws = (short*)d_ws;
    short* vws = (short*)((char*)d_ws + kbytes);
    unsigned long long* mws = (unsigned long long*)((char*)d_ws + 2 * kbytes);
    hipLaunchKernelGGL(preconv_kernel, dim3(1024), dim3(256), 0, stream,
                       K, V, km, kws, vws, mws);
    if (ws_size >= need2) {
      float* Ow = (float*)((char*)d_ws + need1);
      float* Mw = (float*)((char*)d_ws + need1 + owbytes);
      float* Lw = (float*)((char*)d_ws + need1 + owbytes + mlbytes);
      hipLaunchKernelGGL(attn_fwd_v3, dim3(1024), dim3(256), 0, stream,
                         Q, kws, vws, mws, Out, Ow, Mw, Lw, 2);
      hipLaunchKernelGGL(combine_kernel, dim3(2048), dim3(256), 0, stream,
                         Ow, Mw, Lw, Out);
    } else {
      hipLaunchKernelGGL(attn_fwd_v3, dim3(512), dim3(256), 0, stream,
                         Q, kws, vws, mws, Out, (float*)d_ws, (float*)d_ws,
                         (float*)d_ws, 1);
    }
  } else {
    hipLaunchKernelGGL(attn_fwd_kernel, dim3(512), dim3(256), 0, stream,
                       Q, K, V, qm, km, Out);
  }
}

// Round 8
// 125.189 us; speedup vs baseline: 1.1832x; 1.1832x over previous
//
#include <hip/hip_runtime.h>
#include <hip/hip_bf16.h>

#define N_B 2
#define L_Q 2048
#define S_K 2048
#define N_H 8
#define D_H 64
#define HD  512   /* N_H * D_H */
#define KVB 64
#define NT  32    /* kv tiles total */
#define RS  72    /* pl row stride in bf16 elems */
#define PQT ((size_t)N_B * L_Q * N_H)   /* 32768 q-rows */
#define LOG2E 1.4426950408889634f
#define DEFER_THR 11.5f   /* log2-domain defer-max threshold (~e^8) */

typedef __attribute__((ext_vector_type(8))) short bf16x8;
typedef __attribute__((ext_vector_type(4))) short short4v;
typedef __attribute__((ext_vector_type(4))) float f32x4;

__device__ __forceinline__ short f2bf(float f) {
  union { float f; unsigned u; } v; v.f = f;
  return (short)((v.u + 0x7FFFu + ((v.u >> 16) & 1u)) >> 16);
}
__device__ __forceinline__ float bf2f(short s) {
  union { unsigned u; float f; } w; w.u = ((unsigned)(unsigned short)s) << 16;
  return w.f;
}
__device__ __forceinline__ bf16x8 pack8(float4 a, float4 b) {
  bf16x8 t;
  t[0]=f2bf(a.x); t[1]=f2bf(a.y); t[2]=f2bf(a.z); t[3]=f2bf(a.w);
  t[4]=f2bf(b.x); t[5]=f2bf(b.y); t[6]=f2bf(b.z); t[7]=f2bf(b.w);
  return t;
}

// ---------------- pre-convert: fp32 K,V -> bf16 ws; kv_mask -> bitfield ----
__global__ __launch_bounds__(256)
void preconv_kernel(const float* __restrict__ K, const float* __restrict__ V,
                    const int* __restrict__ kvm,
                    short* __restrict__ kws, short* __restrict__ vws,
                    unsigned long long* __restrict__ mws) {
  const size_t i = (size_t)blockIdx.x * 256 + threadIdx.x;
  const float4* kp = (const float4*)K + i * 2;
  float4 a = kp[0], b = kp[1];
  *(bf16x8*)(kws + i * 8) = pack8(a, b);
  const float4* vp = (const float4*)V + i * 2;
  float4 c = vp[0], d = vp[1];
  *(bf16x8*)(vws + i * 8) = pack8(c, d);
  if (blockIdx.x == 0 && threadIdx.x < (N_B * S_K / 64)) {
    const int* src = kvm + threadIdx.x * 64;
    unsigned long long m = 0;
    #pragma unroll 8
    for (int bb = 0; bb < 64; ++bb) m |= (src[bb] ? 1ull : 0ull) << bb;
    mws[threadIdx.x] = m;
  }
}

// ---------------- main: 256 threads (4 waves x 16 q-rows), dbuf LDS --------
// spbits in {0,1,2}: 2^spbits KV-splits. spbits>0: raw partials (log2-domain m)
// to ws; spbits==0: normalized output directly.
__global__ __launch_bounds__(256, 3)
void attn_fwd_v4(const float* __restrict__ Q, const short* __restrict__ Kb,
                 const short* __restrict__ Vb,
                 const unsigned long long* __restrict__ mbits,
                 float* __restrict__ Out,
                 float* __restrict__ Ow, float* __restrict__ Mw,
                 float* __restrict__ Lw, int spbits) {
  // kt: 2 bufs x [64 rows x 128B], XOR-swizzled (byte ^= (row&7)<<4)
  // vt: 2 bufs x subtiled [k/4][d/16][4][16] for ds_read_b64_tr_b16
  __shared__ __align__(128) short kt[2 * 4096];
  __shared__ __align__(128) short vt[2 * 4096];
  __shared__ __align__(16)  short pl[4][16 * RS];

  const int tid  = threadIdx.x;
  const int wid  = tid >> 6;
  const int lane = tid & 63;
  const int l16  = lane & 15;
  const int lg   = lane >> 4;

  // bijective XCD swizzle (gridDim %8==0): same (n,h) clusters on one XCD
  const int per_xcd = gridDim.x >> 3;
  const int logical = (blockIdx.x & 7) * per_xcd + (blockIdx.x >> 3);
  const int qb   = logical & 31;
  const int rest = logical >> 5;
  const int sp   = rest & ((1 << spbits) - 1);
  const int nh   = rest >> spbits;
  const int n  = nh >> 3;
  const int h  = nh & 7;
  const int q0 = qb * 64 + wid * 16;
  const int tps = NT >> spbits;
  const int t0 = sp * tps, t1 = t0 + tps;

  const float* Qn = Q + ((size_t)n * L_Q) * HD + h * D_H;
  const char*  Kn = (const char*)(Kb + ((size_t)n * S_K) * HD + h * D_H); // row stride 1024B
  const char*  Vn = (const char*)(Vb + ((size_t)n * S_K) * HD + h * D_H);

  // ---- per-lane staging offsets (2 chunks of 1024B per wave per tensor) ----
  int koffb[2], voffb[2];
  #pragma unroll
  for (int i = 0; i < 2; ++i) {
    const int p   = (wid * 2 + i) * 1024 + lane * 16;   // phys byte in 8KB tile
    const int row = p >> 7;
    const int cb  = (p & 127) ^ ((row & 7) << 4);       // inverse of read swizzle
    koffb[i] = row * 1024 + cb;
    const int k  = ((p >> 9) << 2) | ((p >> 5) & 3);    // subtile decode
    const int d  = (((p >> 7) & 3) << 4) | ((p >> 1) & 15);
    voffb[i] = k * 1024 + d * 2;
  }

  // ---- Q fragments (A-layout: row l16, k = lg*8+i, +32 per chunk) ----
  // scale = softmax_temp * LOG2E so scores land in log2 domain.
  bf16x8 qf[2];
  {
    const float sc_q = 0.125f * LOG2E;
    const float* qp = Qn + (size_t)(q0 + l16) * HD + lg * 8;
    #pragma unroll
    for (int c = 0; c < 2; ++c) {
      float4 a = *(const float4*)(qp + c * 32);
      float4 b = *(const float4*)(qp + c * 32 + 4);
      float4 as, bs;
      as.x=a.x*sc_q; as.y=a.y*sc_q; as.z=a.z*sc_q; as.w=a.w*sc_q;
      bs.x=b.x*sc_q; bs.y=b.y*sc_q; bs.z=b.z*sc_q; bs.w=b.w*sc_q;
      qf[c] = pack8(as, bs);
    }
  }

  // ones B-fragment (bf16 1.0) for MFMA row-sum
  bf16x8 onesf;
  #pragma unroll
  for (int i = 0; i < 8; ++i) onesf[i] = (short)0x3F80;

  // per-lane K-frag read addrs (bytes within one 8KB buffer), swizzled
  const int swz    = (l16 & 7) << 4;
  const int kaddrA = l16 * 128 + ((lg * 16) ^ swz);
  const int kaddrB = l16 * 128 + ((64 + lg * 16) ^ swz);
  const int vlane  = lg * 1024 + l16 * 8;   // tr-read per-lane base
  const unsigned vt0 = (unsigned)(size_t)(__attribute__((address_space(3))) char*)((char*)&vt[0]);

  f32x4 o[4];
  #pragma unroll
  for (int g = 0; g < 4; ++g) o[g] = (f32x4){0.f, 0.f, 0.f, 0.f};
  f32x4 ls = (f32x4){0.f, 0.f, 0.f, 0.f};   // row-sum accumulator (via MFMA)
  float m_run[4];
  #pragma unroll
  for (int r = 0; r < 4; ++r) m_run[r] = 0.f;   // defer-max init (log2 units)

  short* pw = pl[wid];

  #define ISSUE(t_) do {                                                          \
    const int bs_ = ((t_) & 1) * 8192;                                            \
    const char* ks_ = Kn + (size_t)(t_) * 65536;                                  \
    const char* vs_ = Vn + (size_t)(t_) * 65536;                                  \
    _Pragma("unroll")                                                             \
    for (int i_ = 0; i_ < 2; ++i_) {                                              \
      __builtin_amdgcn_global_load_lds(                                           \
        (const __attribute__((address_space(1))) void*)(ks_ + koffb[i_]),         \
        (__attribute__((address_space(3))) void*)((char*)kt + bs_ + (wid*2+i_)*1024), \
        16, 0, 0);                                                                \
      __builtin_amdgcn_global_load_lds(                                           \
        (const __attribute__((address_space(1))) void*)(vs_ + voffb[i_]),         \
        (__attribute__((address_space(3))) void*)((char*)vt + bs_ + (wid*2+i_)*1024), \
        16, 0, 0);                                                                \
    }                                                                             \
  } while (0)

  ISSUE(t0);

  for (int t = t0; t < t1; ++t) {
    __syncthreads();            // drains vmcnt -> buf[t&1] staged; prev reads done
    if (t + 1 < t1) ISSUE(t + 1);
    const int bo = (t & 1) * 8192;

    // ---- QK^T (log2 domain) ----
    f32x4 sc[4];
    #pragma unroll
    for (int g = 0; g < 4; ++g) {
      bf16x8 kb0 = *(const bf16x8*)((const char*)kt + bo + g * 2048 + kaddrA);
      bf16x8 kb1 = *(const bf16x8*)((const char*)kt + bo + g * 2048 + kaddrB);
      f32x4 z = (f32x4){0.f, 0.f, 0.f, 0.f};
      z = __builtin_amdgcn_mfma_f32_16x16x32_bf16(qf[0], kb0, z, 0, 0, 0);
      z = __builtin_amdgcn_mfma_f32_16x16x32_bf16(qf[1], kb1, z, 0, 0, 0);
      sc[g] = z;
    }

    // ---- kv mask (bitfield, wave-uniform load) ----
    const unsigned long long mb = mbits[n * NT + t];
    #pragma unroll
    for (int g = 0; g < 4; ++g) {
      if (!((mb >> (g * 16 + l16)) & 1ull)) {
        #pragma unroll
        for (int r = 0; r < 4; ++r) sc[g][r] = -3e38f;
      }
    }

    // ---- defer-max: skip rescale unless some row max exceeds m + THR ----
    float pr[4];
    #pragma unroll
    for (int r = 0; r < 4; ++r)
      pr[r] = fmaxf(fmaxf(sc[0][r], sc[1][r]), fmaxf(sc[2][r], sc[3][r]));
    bool ok = (pr[0] <= m_run[0] + DEFER_THR) & (pr[1] <= m_run[1] + DEFER_THR) &
              (pr[2] <= m_run[2] + DEFER_THR) & (pr[3] <= m_run[3] + DEFER_THR);
    if (!__all(ok)) {
      // full path: shfl row max, update m, rescale o and ls
      float alpha[4];
      #pragma unroll
      for (int r = 0; r < 4; ++r) {
        float v = pr[r];
        v = fmaxf(v, __shfl_xor(v, 1));
        v = fmaxf(v, __shfl_xor(v, 2));
        v = fmaxf(v, __shfl_xor(v, 4));
        v = fmaxf(v, __shfl_xor(v, 8));
        float mn = fmaxf(m_run[r], v);
        alpha[r] = __builtin_amdgcn_exp2f(m_run[r] - mn);
        m_run[r] = mn;
      }
      #pragma unroll
      for (int g = 0; g < 4; ++g)
        #pragma unroll
        for (int r = 0; r < 4; ++r) o[g][r] *= alpha[r];
      #pragma unroll
      for (int r = 0; r < 4; ++r) ls[r] *= alpha[r];
    }

    // ---- P = exp2(sc - m) -> bf16 ----
    short pb[4][4];
    #pragma unroll
    for (int g = 0; g < 4; ++g)
      #pragma unroll
      for (int r = 0; r < 4; ++r)
        pb[g][r] = f2bf(__builtin_amdgcn_exp2f(sc[g][r] - m_run[r]));

    // ---- P: D-layout -> A-layout via per-wave LDS buffer (no barrier) ----
    #pragma unroll
    for (int g = 0; g < 4; ++g)
      #pragma unroll
      for (int r = 0; r < 4; ++r)
        pw[(lg * 4 + r) * RS + g * 16 + l16] = pb[g][r];

    bf16x8 pa0 = *(const bf16x8*)&pw[l16 * RS + lg * 8];
    bf16x8 pa1 = *(const bf16x8*)&pw[l16 * RS + 32 + lg * 8];

    // ---- row-sum via MFMA (ones B-frag): ls[r] += sum_kv P[row][kv] ----
    ls = __builtin_amdgcn_mfma_f32_16x16x32_bf16(pa0, onesf, ls, 0, 0, 0);
    ls = __builtin_amdgcn_mfma_f32_16x16x32_bf16(pa1, onesf, ls, 0, 0, 0);

    // ---- V B-fragments via HW transpose read ----
    const unsigned va = vt0 + (unsigned)(bo + vlane);
    #define TRRD(dst, off) asm volatile("ds_read_b64_tr_b16 %0, %1 offset:" off \
                                        : "=v"(dst) : "v"(va))
    short4v w0la, w0lb, w0ha, w0hb, w1la, w1lb, w1ha, w1hb;
    short4v w2la, w2lb, w2ha, w2hb, w3la, w3lb, w3ha, w3hb;
    TRRD(w0la, "0");   TRRD(w0lb, "512"); TRRD(w0ha, "4096"); TRRD(w0hb, "4608");
    TRRD(w1la, "128"); TRRD(w1lb, "640"); TRRD(w1ha, "4224"); TRRD(w1hb, "4736");
    TRRD(w2la, "256"); TRRD(w2lb, "768"); TRRD(w2ha, "4352"); TRRD(w2hb, "4864");
    TRRD(w3la, "384"); TRRD(w3lb, "896"); TRRD(w3ha, "4480"); TRRD(w3hb, "4992");
    asm volatile("s_waitcnt lgkmcnt(0)" ::: "memory");
    __builtin_amdgcn_sched_barrier(0);

    bf16x8 v0l = __builtin_shufflevector(w0la, w0lb, 0,1,2,3,4,5,6,7);
    bf16x8 v0h = __builtin_shufflevector(w0ha, w0hb, 0,1,2,3,4,5,6,7);
    bf16x8 v1l = __builtin_shufflevector(w1la, w1lb, 0,1,2,3,4,5,6,7);
    bf16x8 v1h = __builtin_shufflevector(w1ha, w1hb, 0,1,2,3,4,5,6,7);
    bf16x8 v2l = __builtin_shufflevector(w2la, w2lb, 0,1,2,3,4,5,6,7);
    bf16x8 v2h = __builtin_shufflevector(w2ha, w2hb, 0,1,2,3,4,5,6,7);
    bf16x8 v3l = __builtin_shufflevector(w3la, w3lb, 0,1,2,3,4,5,6,7);
    bf16x8 v3h = __builtin_shufflevector(w3ha, w3hb, 0,1,2,3,4,5,6,7);

    o[0] = __builtin_amdgcn_mfma_f32_16x16x32_bf16(pa0, v0l, o[0], 0, 0, 0);
    o[0] = __builtin_amdgcn_mfma_f32_16x16x32_bf16(pa1, v0h, o[0], 0, 0, 0);
    o[1] = __builtin_amdgcn_mfma_f32_16x16x32_bf16(pa0, v1l, o[1], 0, 0, 0);
    o[1] = __builtin_amdgcn_mfma_f32_16x16x32_bf16(pa1, v1h, o[1], 0, 0, 0);
    o[2] = __builtin_amdgcn_mfma_f32_16x16x32_bf16(pa0, v2l, o[2], 0, 0, 0);
    o[2] = __builtin_amdgcn_mfma_f32_16x16x32_bf16(pa1, v2h, o[2], 0, 0, 0);
    o[3] = __builtin_amdgcn_mfma_f32_16x16x32_bf16(pa0, v3l, o[3], 0, 0, 0);
    o[3] = __builtin_amdgcn_mfma_f32_16x16x32_bf16(pa1, v3h, o[3], 0, 0, 0);
  }

  // ---- epilogue ----
  if (spbits > 0) {
    #pragma unroll
    for (int r = 0; r < 4; ++r) {
      const size_t row = ((size_t)n * L_Q + q0 + lg * 4 + r) * N_H + h;
      const size_t ob  = ((size_t)sp * PQT + row) * D_H;
      #pragma unroll
      for (int gd = 0; gd < 4; ++gd)
        Ow[ob + gd * 16 + l16] = o[gd][r];
      if (l16 == 0) { Mw[sp * PQT + row] = m_run[r]; Lw[sp * PQT + row] = ls[r]; }
    }
  } else {
    float* op = Out + ((size_t)n * L_Q + q0) * HD + h * D_H;
    float inv[4];
    #pragma unroll
    for (int r = 0; r < 4; ++r) inv[r] = 1.0f / ls[r];
    #pragma unroll
    for (int gd = 0; gd < 4; ++gd)
      #pragma unroll
      for (int r = 0; r < 4; ++r)
        op[(size_t)(lg * 4 + r) * HD + gd * 16 + l16] = o[gd][r] * inv[r];
  }
}

// ---------------- combine: merge nsp KV-split partials (log2-domain m) ----
__global__ __launch_bounds__(256)
void combine_kernel(const float* __restrict__ Ow, const float* __restrict__ Mw,
                    const float* __restrict__ Lw, float* __restrict__ Out,
                    int nsp) {
  const int gid = blockIdx.x * 256 + threadIdx.x;   // 524288 threads
  const size_t rid = (size_t)(gid >> 4);            // q-row id in [n][q][h] order
  const int d0 = (gid & 15) << 2;
  float M = -3e38f;
  for (int j = 0; j < nsp; ++j) M = fmaxf(M, Mw[j * PQT + rid]);
  float lsum = 0.f;
  float ax = 0.f, ay = 0.f, az = 0.f, aw = 0.f;
  for (int j = 0; j < nsp; ++j) {
    float w = __builtin_amdgcn_exp2f(Mw[j * PQT + rid] - M);
    lsum += Lw[j * PQT + rid] * w;
    const float4 ov = *(const float4*)(Ow + (j * PQT + rid) * D_H + d0);
    ax += ov.x * w; ay += ov.y * w; az += ov.z * w; aw += ov.w * w;
  }
  const float inv = 1.0f / lsum;
  float4 r;
  r.x = ax * inv; r.y = ay * inv; r.z = az * inv; r.w = aw * inv;
  *(float4*)(Out + rid * D_H + d0) = r;
}

// ---------------- fallback (Round-3 kernel, proven, ws-free) ---------------
__global__ __launch_bounds__(256, 2)
void attn_fwd_kernel(const float* __restrict__ Q, const float* __restrict__ K,
                     const float* __restrict__ V,
                     const int* __restrict__ q_mask,
                     const int* __restrict__ kv_mask,
                     float* __restrict__ Out) {
  __shared__ __align__(16) short kts[KVB * RS];
  __shared__ __align__(16) short vts[D_H * RS];
  __shared__ __align__(16) short pls[4][16 * RS];
  const int tid = threadIdx.x, wid = tid >> 6, lane = tid & 63;
  const int l16 = lane & 15, lg = lane >> 4;
  const int bid = blockIdx.x, nh = bid >> 5, qb = bid & 31;
  const int n = nh >> 3, h = nh & 7, q0 = qb * 64 + wid * 16;
  const float* Qb = Q + ((size_t)n * L_Q) * HD + h * D_H;
  const float* Kb = K + ((size_t)n * S_K) * HD + h * D_H;
  const float* Vb = V + ((size_t)n * S_K) * HD + h * D_H;
  const int* km = kv_mask + (size_t)n * S_K;
  (void)q_mask;
  bf16x8 qf[2];
  {
    const float* qp = Qb + (size_t)(q0 + l16) * HD + lg * 8;
    #pragma unroll
    for (int c = 0; c < 2; ++c) {
      float4 a = *(const float4*)(qp + c * 32);
      float4 b = *(const float4*)(qp + c * 32 + 4);
      float4 as, bs;
      as.x=a.x*0.125f; as.y=a.y*0.125f; as.z=a.z*0.125f; as.w=a.w*0.125f;
      bs.x=b.x*0.125f; bs.y=b.y*0.125f; bs.z=b.z*0.125f; bs.w=b.w*0.125f;
      qf[c] = pack8(as, bs);
    }
  }
  f32x4 o[4];
  #pragma unroll
  for (int g = 0; g < 4; ++g) o[g] = (f32x4){0.f, 0.f, 0.f, 0.f};
  float m_run[4], l_run[4];
  #pragma unroll
  for (int r = 0; r < 4; ++r) { m_run[r] = -3e38f; l_run[r] = 0.f; }
  for (int s0 = 0; s0 < S_K; s0 += KVB) {
    __syncthreads();
    {
      const int cid = tid << 1, row = cid >> 3, c0 = cid & 7;
      const float* kp = Kb + (size_t)(s0 + row) * HD + c0 * 8;
      float4 f0 = *(const float4*)(kp), f1 = *(const float4*)(kp + 4);
      float4 f2 = *(const float4*)(kp + 8), f3 = *(const float4*)(kp + 12);
      *(bf16x8*)&kts[row * RS + c0 * 8]     = pack8(f0, f1);
      *(bf16x8*)&kts[row * RS + c0 * 8 + 8] = pack8(f2, f3);
    }
    {
      const int kv = tid >> 2, dc = tid & 3;
      const float* vp = Vb + (size_t)(s0 + kv) * HD + dc * 16;
      float4 f0 = *(const float4*)(vp), f1 = *(const float4*)(vp + 4);
      float4 f2 = *(const float4*)(vp + 8), f3 = *(const float4*)(vp + 12);
      float tv[16] = { f0.x,f0.y,f0.z,f0.w, f1.x,f1.y,f1.z,f1.w,
                       f2.x,f2.y,f2.z,f2.w, f3.x,f3.y,f3.z,f3.w };
      short* dst = &vts[(dc * 16) * RS + kv];
      #pragma unroll
      for (int j = 0; j < 16; ++j) dst[j * RS] = f2bf(tv[j]);
    }
    __syncthreads();
    f32x4 sc[4];
    #pragma unroll
    for (int g = 0; g < 4; ++g) {
      bf16x8 kb0 = *(const bf16x8*)&kts[(g*16 + l16) * RS + lg * 8];
      bf16x8 kb1 = *(const bf16x8*)&kts[(g*16 + l16) * RS + 32 + lg * 8];
      f32x4 z = (f32x4){0.f, 0.f, 0.f, 0.f};
      z = __builtin_amdgcn_mfma_f32_16x16x32_bf16(qf[0], kb0, z, 0, 0, 0);
      z = __builtin_amdgcn_mfma_f32_16x16x32_bf16(qf[1], kb1, z, 0, 0, 0);
      sc[g] = z;
    }
    #pragma unroll
    for (int g = 0; g < 4; ++g) {
      float b = km[s0 + g*16 + l16] ? 0.f : -3e38f;
      #pragma unroll
      for (int r = 0; r < 4; ++r) sc[g][r] += b;
    }
    float mt[4];
    #pragma unroll
    for (int r = 0; r < 4; ++r) {
      float v = fmaxf(fmaxf(sc[0][r], sc[1][r]), fmaxf(sc[2][r], sc[3][r]));
      v = fmaxf(v, __shfl_xor(v, 1)); v = fmaxf(v, __shfl_xor(v, 2));
      v = fmaxf(v, __shfl_xor(v, 4)); v = fmaxf(v, __shfl_xor(v, 8));
      mt[r] = v;
    }
    float alpha[4];
    #pragma unroll
    for (int r = 0; r < 4; ++r) {
      float mn = fmaxf(m_run[r], mt[r]);
      alpha[r] = __builtin_amdgcn_exp2f((m_run[r] - mn) * LOG2E);
      m_run[r] = mn;
    }
    float rsum[4] = {0.f, 0.f, 0.f, 0.f};
    short pb[4][4];
    #pragma unroll
    for (int g = 0; g < 4; ++g)
      #pragma unroll
      for (int r = 0; r < 4; ++r) {
        float p = __builtin_amdgcn_exp2f((sc[g][r] - m_run[r]) * LOG2E);
        short s = f2bf(p); pb[g][r] = s; rsum[r] += bf2f(s);
      }
    #pragma unroll
    for (int r = 0; r < 4; ++r) {
      float v = rsum[r];
      v += __shfl_xor(v, 1); v += __shfl_xor(v, 2);
      v += __shfl_xor(v, 4); v += __shfl_xor(v, 8);
      l_run[r] = l_run[r] * alpha[r] + v;
    }
    #pragma unroll
    for (int g = 0; g < 4; ++g)
      #pragma unroll
      for (int r = 0; r < 4; ++r) o[g][r] *= alpha[r];
    short* pwf = pls[wid];
    #pragma unroll
    for (int g = 0; g < 4; ++g)
      #pragma unroll
      for (int r = 0; r < 4; ++r)
        pwf[(lg*4 + r) * RS + g*16 + l16] = pb[g][r];
    __syncthreads();
    bf16x8 pa0 = *(const bf16x8*)&pwf[l16 * RS + lg * 8];
    bf16x8 pa1 = *(const bf16x8*)&pwf[l16 * RS + 32 + lg * 8];
    #pragma unroll
    for (int gd = 0; gd < 4; ++gd) {
      bf16x8 vb0 = *(const bf16x8*)&vts[(gd*16 + l16) * RS + lg * 8];
      bf16x8 vb1 = *(const bf16x8*)&vts[(gd*16 + l16) * RS + 32 + lg * 8];
      o[gd] = __builtin_amdgcn_mfma_f32_16x16x32_bf16(pa0, vb0, o[gd], 0, 0, 0);
      o[gd] = __builtin_amdgcn_mfma_f32_16x16x32_bf16(pa1, vb1, o[gd], 0, 0, 0);
    }
  }
  float* op = Out + ((size_t)n * L_Q + q0) * HD + h * D_H;
  float inv[4];
  #pragma unroll
  for (int r = 0; r < 4; ++r) inv[r] = 1.0f / l_run[r];
  #pragma unroll
  for (int gd = 0; gd < 4; ++gd)
    #pragma unroll
    for (int r = 0; r < 4; ++r)
      op[(size_t)(lg*4 + r) * HD + gd*16 + l16] = o[gd][r] * inv[r];
}

extern "C" void kernel_launch(void* const* d_in, const int* in_sizes, int n_in,
                              void* d_out, int out_size, void* d_ws, size_t ws_size,
                              hipStream_t stream) {
  const float* Q = (const float*)d_in[0];
  const float* K = (const float*)d_in[1];
  const float* V = (const float*)d_in[2];
  const int* qm = (const int*)d_in[3];
  const int* km = (const int*)d_in[4];
  float* Out = (float*)d_out;
  (void)in_sizes; (void)n_in; (void)out_size;

  const size_t kbytes = (size_t)N_B * S_K * HD * 2;             // 4 MiB
  const size_t need1  = 2 * kbytes + 1024;                       // preconv tier
  const size_t per_sp = PQT * D_H * sizeof(float)                // Ow slice
                      + 2 * PQT * sizeof(float);                 // Mw + Lw slice

  if (ws_size >= need1) {
    short* kws = (short*)d_ws;
    short* vws = (short*)((char*)d_ws + kbytes);
    unsigned long long* mws = (unsigned long long*)((char*)d_ws + 2 * kbytes);
    hipLaunchKernelGGL(preconv_kernel, dim3(1024), dim3(256), 0, stream,
                       K, V, km, kws, vws, mws);

    int spbits = 0;
    if (ws_size >= need1 + 4 * per_sp)      spbits = 2;
    else if (ws_size >= need1 + 2 * per_sp) spbits = 1;

    if (spbits > 0) {
      const int nsp = 1 << spbits;
      float* Mw = (float*)((char*)d_ws + need1);
      float* Lw = Mw + (size_t)nsp * PQT;
      float* Ow = Lw + (size_t)nsp * PQT;
      hipLaunchKernelGGL(attn_fwd_v4, dim3(512 * nsp), dim3(256), 0, stream,
                         Q, kws, vws, mws, Out, Ow, Mw, Lw, spbits);
      hipLaunchKernelGGL(combine_kernel, dim3(2048), dim3(256), 0, stream,
                         Ow, Mw, Lw, Out, nsp);
    } else {
      hipLaunchKernelGGL(attn_fwd_v4, dim3(512), dim3(256), 0, stream,
                         Q, kws, vws, mws, Out, (float*)d_ws, (float*)d_ws,
                         (float*)d_ws, 0);
    }
  } else {
    hipLaunchKernelGGL(attn_fwd_kernel, dim3(512), dim3(256), 0, stream,
                       Q, K, V, qm, km, Out);
  }
}

// Round 11
// 122.111 us; speedup vs baseline: 1.2130x; 1.0252x over previous
//
#include <hip/hip_runtime.h>
#include <hip/hip_bf16.h>

#define N_B 2
#define L_Q 2048
#define S_K 2048
#define N_H 8
#define D_H 64
#define HD  512   /* N_H * D_H */
#define KVB 64
#define NT  32    /* kv tiles total */
#define NSP 3     /* kv splits (768 blocks = 3/CU exactly) */
#define RS  72    /* fallback kernel LDS pad */
#define PQT ((size_t)N_B * L_Q * N_H)   /* 32768 q-rows */
#define LOG2E 1.4426950408889634f
#define DEFER_THR 11.5f

typedef __attribute__((ext_vector_type(8)))  short bf16x8;
typedef __attribute__((ext_vector_type(4)))  short short4v;
typedef __attribute__((ext_vector_type(4)))  float f32x4;
typedef __attribute__((ext_vector_type(16))) float f32x16;
typedef __attribute__((ext_vector_type(4)))  unsigned int u32x4;

__device__ __forceinline__ short f2bf(float f) {
  union { float f; unsigned u; } v; v.f = f;
  return (short)((v.u + 0x7FFFu + ((v.u >> 16) & 1u)) >> 16);
}
__device__ __forceinline__ float bf2f(short s) {
  union { unsigned u; float f; } w; w.u = ((unsigned)(unsigned short)s) << 16;
  return w.f;
}
__device__ __forceinline__ bf16x8 pack8(float4 a, float4 b) {
  bf16x8 t;
  t[0]=f2bf(a.x); t[1]=f2bf(a.y); t[2]=f2bf(a.z); t[3]=f2bf(a.w);
  t[4]=f2bf(b.x); t[5]=f2bf(b.y); t[6]=f2bf(b.z); t[7]=f2bf(b.w);
  return t;
}
__device__ __forceinline__ unsigned cvtpk(float a, float b) {
  unsigned d;
  asm("v_cvt_pk_bf16_f32 %0, %1, %2" : "=v"(d) : "v"(a), "v"(b));
  return d;
}

// ---- pre-convert: K -> bf16 [n][kv][h][d]; V -> bf16 V^T [n][h][d][kv];
// ---- kv_mask -> 64-bit-per-tile bitfield.
__global__ __launch_bounds__(256)
void preconv_kernel(const float* __restrict__ K, const float* __restrict__ V,
                    const int* __restrict__ kvm,
                    short* __restrict__ kws, short* __restrict__ vtws,
                    unsigned long long* __restrict__ mws) {
  const size_t i = (size_t)blockIdx.x * 256 + threadIdx.x;  // 262144 threads
  // K: 8 contiguous elems, coalesced read+write
  const float4* kp = (const float4*)K + i * 2;
  float4 a = kp[0], b = kp[1];
  *(bf16x8*)(kws + i * 8) = pack8(a, b);
  // V^T: 8 contiguous source elems (one (n,kv,h,d0..d0+7) run) scattered to [d][kv]
  {
    const size_t e0 = i * 8;
    const float4* vp = (const float4*)(V + e0);
    float4 c = vp[0], d = vp[1];
    const int n   = (int)(e0 >> 20);            // /(2048*512)
    const int rem = (int)(e0 & 1048575u);
    const int kv  = rem >> 9;
    const int hd  = rem & 511;
    const int h   = hd >> 6, d0 = hd & 63;
    short* dst = vtws + ((size_t)((n * 8 + h) * 64 + d0)) * 2048 + kv;
    float tv[8] = { c.x,c.y,c.z,c.w, d.x,d.y,d.z,d.w };
    #pragma unroll
    for (int j = 0; j < 8; ++j) dst[(size_t)j * 2048] = f2bf(tv[j]);
  }
  if (blockIdx.x == 0 && threadIdx.x < (N_B * S_K / 64)) {
    const int* src = kvm + threadIdx.x * 64;
    unsigned long long m = 0;
    #pragma unroll 8
    for (int bb = 0; bb < 64; ++bb) m |= (src[bb] ? 1ull : 0ull) << bb;
    mws[threadIdx.x] = m;
  }
}

// ---- main: 4 waves x 32 q-rows (128 q/block); 32x32x16 swapped-QK^T;
// ---- lane-local softmax; P packed in-register; always writes bf16 partials.
__global__ __launch_bounds__(256, 3)
void attn_fwd32(const float* __restrict__ Q, const short* __restrict__ Kb,
                const short* __restrict__ Vtb,
                const unsigned long long* __restrict__ mbits,
                short* __restrict__ Owb, float* __restrict__ Mw,
                float* __restrict__ Lw) {
  // kt: [64 kv][128B] rows, XOR-swizzled (byte ^= (row&7)<<4), dbuf
  // vt: [64 d ][128B] rows (V^T), same swizzle, dbuf
  __shared__ __align__(128) short kt[2 * 4096];
  __shared__ __align__(128) short vt[2 * 4096];

  const int tid  = threadIdx.x;
  const int wid  = tid >> 6;
  const int lane = tid & 63;
  const int l31  = lane & 31;
  const int hi   = lane >> 5;

  // bijective XCD swizzle (768 % 8 == 0); qb fastest -> (n,h,sp) clusters per XCD
  const int logical = (blockIdx.x & 7) * 96 + (blockIdx.x >> 3);
  const int qb   = logical & 15;
  const int rest = logical >> 4;        // 0..47
  const int sp   = rest % NSP;
  const int nh   = rest / NSP;          // 0..15
  const int n = nh >> 3;
  const int h = nh & 7;
  const int q0 = qb * 128 + wid * 32;
  const int t0 = sp * 11;
  const int t1 = (sp == 2) ? NT : (t0 + 11);

  const float* Qn  = Q + ((size_t)n * L_Q) * HD + h * D_H;
  const char*  Kn  = (const char*)(Kb + ((size_t)n * S_K) * HD + h * D_H); // row stride 1024B
  const char*  Vtn = (const char*)(Vtb + ((size_t)(n * 8 + h) * 64) * 2048); // row stride 4096B

  // staging offsets: 2 chunks of 16B per thread per tensor (8KB tile / 256thr / 16B)
  int koffb[2], voffb[2];
  #pragma unroll
  for (int i = 0; i < 2; ++i) {
    const int p   = tid * 16 + i * 4096;           // phys byte in 8KB tile
    const int row = p >> 7;
    const int g   = (p & 127) ^ ((row & 7) << 4);  // inverse of read swizzle
    koffb[i] = row * 1024 + g;                     // K global: row=kv, 1024B stride
    voffb[i] = row * 4096 + g;                     // V^T global: row=d, 4096B stride
  }

  // Q B-frags: col=q=l31, k(d) = dc*16 + hi*8 + i ; scale folds temp*LOG2E
  bf16x8 qf[4];
  {
    const float sq = 0.125f * LOG2E;
    const float* qp = Qn + (size_t)(q0 + l31) * HD + hi * 8;
    #pragma unroll
    for (int dc = 0; dc < 4; ++dc) {
      float4 a = *(const float4*)(qp + dc * 16);
      float4 b = *(const float4*)(qp + dc * 16 + 4);
      float4 as, bs;
      as.x=a.x*sq; as.y=a.y*sq; as.z=a.z*sq; as.w=a.w*sq;
      bs.x=b.x*sq; bs.y=b.y*sq; bs.z=b.z*sq; bs.w=b.w*sq;
      qf[dc] = pack8(as, bs);
    }
  }

  const int swz = (l31 & 7) << 4;
  f32x16 o0 = {}, o1 = {};
  float m = 0.f, ls = 0.f;    // defer-max init (log2 domain); own-half row sum

  #define ISSUE(t_) do {                                                          \
    const int bs_ = ((t_) & 1) * 8192;                                            \
    const char* ks_ = Kn + (size_t)(t_) * 65536;                                  \
    const char* vs_ = Vtn + (size_t)(t_) * 128;                                   \
    _Pragma("unroll")                                                             \
    for (int i_ = 0; i_ < 2; ++i_) {                                              \
      __builtin_amdgcn_global_load_lds(                                           \
        (const __attribute__((address_space(1))) void*)(ks_ + koffb[i_]),         \
        (__attribute__((address_space(3))) void*)((char*)kt + bs_ + wid*1024 + i_*4096), \
        16, 0, 0);                                                                \
      __builtin_amdgcn_global_load_lds(                                           \
        (const __attribute__((address_space(1))) void*)(vs_ + voffb[i_]),         \
        (__attribute__((address_space(3))) void*)((char*)vt + bs_ + wid*1024 + i_*4096), \
        16, 0, 0);                                                                \
    }                                                                             \
  } while (0)

  ISSUE(t0);

  for (int t = t0; t < t1; ++t) {
    __syncthreads();            // vmcnt drained -> buf[t&1] staged
    if (t + 1 < t1) ISSUE(t + 1);
    const int bo = (t & 1) * 8192;

    // ---- QK^T swapped: D[kv][q], col=q=l31; a0=kv 0-31, a1=kv 32-63 ----
    f32x16 a0 = {}, a1 = {};
    #pragma unroll
    for (int dc = 0; dc < 4; ++dc) {
      const int co = (dc * 32 + hi * 16) ^ swz;
      bf16x8 kf0 = *(const bf16x8*)((const char*)kt + bo + l31 * 128 + co);
      bf16x8 kf1 = *(const bf16x8*)((const char*)kt + bo + (32 + l31) * 128 + co);
      a0 = __builtin_amdgcn_mfma_f32_32x32x16_bf16(kf0, qf[dc], a0, 0, 0, 0);
      a1 = __builtin_amdgcn_mfma_f32_32x32x16_bf16(kf1, qf[dc], a1, 0, 0, 0);
    }

    // ---- kv mask (all-true fast path) ----
    const unsigned long long mb = mbits[n * NT + t];
    if (mb != ~0ull) {
      #pragma unroll
      for (int r = 0; r < 16; ++r) {
        const int kv0 = (r & 3) + 8 * (r >> 2) + 4 * hi;
        if (!((mb >> kv0) & 1ull))        a0[r] = -3e38f;
        if (!((mb >> (kv0 + 32)) & 1ull)) a1[r] = -3e38f;
      }
    }

    // ---- defer-max: lane-local partial max; skip rescale when bounded ----
    float pm = a0[0];
    #pragma unroll
    for (int r = 1; r < 16; ++r) pm = fmaxf(pm, a0[r]);
    #pragma unroll
    for (int r = 0; r < 16; ++r) pm = fmaxf(pm, a1[r]);
    if (!__all(pm <= m + DEFER_THR)) {
      float mx = fmaxf(pm, __shfl_xor(pm, 32));
      float mn = fmaxf(m, mx);
      float al = __builtin_amdgcn_exp2f(m - mn);
      m = mn;
      #pragma unroll
      for (int r = 0; r < 16; ++r) { o0[r] *= al; o1[r] *= al; }
      ls *= al;
    }

    // ---- P = exp2(sc - m); own-half row sum ----
    float psum = 0.f;
    #pragma unroll
    for (int r = 0; r < 16; ++r) {
      a0[r] = __builtin_amdgcn_exp2f(a0[r] - m); psum += a0[r];
      a1[r] = __builtin_amdgcn_exp2f(a1[r] - m); psum += a1[r];
    }
    ls += psum;

    // ---- pack P -> A-frags (kv = ks*16 + hi*8 + i per frag) ----
    u32x4 paw[4];
    #pragma unroll
    for (int ks = 0; ks < 4; ++ks) {
      const int ro = (ks & 1) * 8;
      float e0, e1, e2, e3, e4, e5, e6, e7;
      if (ks < 2) { e0=a0[ro]; e1=a0[ro+1]; e2=a0[ro+2]; e3=a0[ro+3];
                    e4=a0[ro+4]; e5=a0[ro+5]; e6=a0[ro+6]; e7=a0[ro+7]; }
      else        { e0=a1[ro]; e1=a1[ro+1]; e2=a1[ro+2]; e3=a1[ro+3];
                    e4=a1[ro+4]; e5=a1[ro+5]; e6=a1[ro+6]; e7=a1[ro+7]; }
      unsigned x = cvtpk(e0, e1), y = cvtpk(e2, e3);
      unsigned u = cvtpk(e4, e5), v = cvtpk(e6, e7);
      unsigned xs = __shfl_xor(x, 32), ys = __shfl_xor(y, 32);
      unsigned us = __shfl_xor(u, 32), vs = __shfl_xor(v, 32);
      u32x4 w;
      w[0] = hi ? us : x;  w[1] = hi ? vs : y;
      w[2] = hi ? u  : xs; w[3] = hi ? v  : ys;
      paw[ks] = w;
    }

    // ---- PV: O[q][d] += P * V ; B-frag = V^T row d, kv-run ----
    #pragma unroll
    for (int ks = 0; ks < 4; ++ks) {
      const bf16x8 pa = *(const bf16x8*)&paw[ks];
      const int co = (ks * 32 + hi * 16) ^ swz;
      bf16x8 vf0 = *(const bf16x8*)((const char*)vt + bo + l31 * 128 + co);
      bf16x8 vf1 = *(const bf16x8*)((const char*)vt + bo + (32 + l31) * 128 + co);
      o0 = __builtin_amdgcn_mfma_f32_32x32x16_bf16(pa, vf0, o0, 0, 0, 0);
      o1 = __builtin_amdgcn_mfma_f32_32x32x16_bf16(pa, vf1, o1, 0, 0, 0);
    }
  }

  // ---- epilogue: raw bf16 partials + per-row m, l ----
  const float lst = ls + __shfl_xor(ls, 32);
  #pragma unroll
  for (int r = 0; r < 16; ++r) {
    const int qrow = q0 + ((r & 3) + 8 * (r >> 2) + 4 * hi);
    const size_t rowidx = ((size_t)n * L_Q + qrow) * N_H + h;
    const size_t ob = ((size_t)sp * PQT + rowidx) * D_H;
    Owb[ob + l31]      = f2bf(o0[r]);
    Owb[ob + 32 + l31] = f2bf(o1[r]);
  }
  if (lane < 32) {
    const int qrow = q0 + lane;
    const size_t rowidx = ((size_t)n * L_Q + qrow) * N_H + h;
    Mw[(size_t)sp * PQT + rowidx] = m;
    Lw[(size_t)sp * PQT + rowidx] = lst;
  }
}

// ---- combine: merge NSP bf16 partials (log2-domain m) ----
__global__ __launch_bounds__(256)
void combine_kernel(const short* __restrict__ Owb, const float* __restrict__ Mw,
                    const float* __restrict__ Lw, float* __restrict__ Out) {
  const int gid = blockIdx.x * 256 + threadIdx.x;   // 524288 threads
  const size_t rid = (size_t)(gid >> 4);
  const int d0 = (gid & 15) << 2;
  float M = fmaxf(fmaxf(Mw[rid], Mw[PQT + rid]), Mw[2 * PQT + rid]);
  float lsum = 0.f, ax = 0.f, ay = 0.f, az = 0.f, aw = 0.f;
  #pragma unroll
  for (int j = 0; j < NSP; ++j) {
    const float w = __builtin_amdgcn_exp2f(Mw[j * PQT + rid] - M);
    lsum += Lw[j * PQT + rid] * w;
    const short4v ov = *(const short4v*)(Owb + (j * PQT + rid) * D_H + d0);
    ax += bf2f(ov[0]) * w; ay += bf2f(ov[1]) * w;
    az += bf2f(ov[2]) * w; aw += bf2f(ov[3]) * w;
  }
  const float inv = 1.0f / lsum;
  float4 r; r.x = ax * inv; r.y = ay * inv; r.z = az * inv; r.w = aw * inv;
  *(float4*)(Out + rid * D_H + d0) = r;
}

// ---- fallback (Round-3 kernel, proven, ws-free) ----
__global__ __launch_bounds__(256, 2)
void attn_fwd_kernel(const float* __restrict__ Q, const float* __restrict__ K,
                     const float* __restrict__ V,
                     const int* __restrict__ q_mask,
                     const int* __restrict__ kv_mask,
                     float* __restrict__ Out) {
  __shared__ __align__(16) short kts[KVB * RS];
  __shared__ __align__(16) short vts[D_H * RS];
  __shared__ __align__(16) short pls[4][16 * RS];
  const int tid = threadIdx.x, wid = tid >> 6, lane = tid & 63;
  const int l16 = lane & 15, lg = lane >> 4;
  const int bid = blockIdx.x, nh = bid >> 5, qb = bid & 31;
  const int n = nh >> 3, h = nh & 7, q0 = qb * 64 + wid * 16;
  const float* Qb = Q + ((size_t)n * L_Q) * HD + h * D_H;
  const float* Kb = K + ((size_t)n * S_K) * HD + h * D_H;
  const float* Vb = V + ((size_t)n * S_K) * HD + h * D_H;
  const int* km = kv_mask + (size_t)n * S_K;
  (void)q_mask;
  bf16x8 qf[2];
  {
    const float* qp = Qb + (size_t)(q0 + l16) * HD + lg * 8;
    #pragma unroll
    for (int c = 0; c < 2; ++c) {
      float4 a = *(const float4*)(qp + c * 32);
      float4 b = *(const float4*)(qp + c * 32 + 4);
      float4 as, bs;
      as.x=a.x*0.125f; as.y=a.y*0.125f; as.z=a.z*0.125f; as.w=a.w*0.125f;
      bs.x=b.x*0.125f; bs.y=b.y*0.125f; bs.z=b.z*0.125f; bs.w=b.w*0.125f;
      qf[c] = pack8(as, bs);
    }
  }
  f32x4 o[4];
  #pragma unroll
  for (int g = 0; g < 4; ++g) o[g] = (f32x4){0.f, 0.f, 0.f, 0.f};
  float m_run[4], l_run[4];
  #pragma unroll
  for (int r = 0; r < 4; ++r) { m_run[r] = -3e38f; l_run[r] = 0.f; }
  for (int s0 = 0; s0 < S_K; s0 += KVB) {
    __syncthreads();
    {
      const int cid = tid << 1, row = cid >> 3, c0 = cid & 7;
      const float* kp = Kb + (size_t)(s0 + row) * HD + c0 * 8;
      float4 f0 = *(const float4*)(kp), f1 = *(const float4*)(kp + 4);
      float4 f2 = *(const float4*)(kp + 8), f3 = *(const float4*)(kp + 12);
      *(bf16x8*)&kts[row * RS + c0 * 8]     = pack8(f0, f1);
      *(bf16x8*)&kts[row * RS + c0 * 8 + 8] = pack8(f2, f3);
    }
    {
      const int kv = tid >> 2, dc = tid & 3;
      const float* vp = Vb + (size_t)(s0 + kv) * HD + dc * 16;
      float4 f0 = *(const float4*)(vp), f1 = *(const float4*)(vp + 4);
      float4 f2 = *(const float4*)(vp + 8), f3 = *(const float4*)(vp + 12);
      float tv[16] = { f0.x,f0.y,f0.z,f0.w, f1.x,f1.y,f1.z,f1.w,
                       f2.x,f2.y,f2.z,f2.w, f3.x,f3.y,f3.z,f3.w };
      short* dst = &vts[(dc * 16) * RS + kv];
      #pragma unroll
      for (int j = 0; j < 16; ++j) dst[j * RS] = f2bf(tv[j]);
    }
    __syncthreads();
    f32x4 sc[4];
    #pragma unroll
    for (int g = 0; g < 4; ++g) {
      bf16x8 kb0 = *(const bf16x8*)&kts[(g*16 + l16) * RS + lg * 8];
      bf16x8 kb1 = *(const bf16x8*)&kts[(g*16 + l16) * RS + 32 + lg * 8];
      f32x4 z = (f32x4){0.f, 0.f, 0.f, 0.f};
      z = __builtin_amdgcn_mfma_f32_16x16x32_bf16(qf[0], kb0, z, 0, 0, 0);
      z = __builtin_amdgcn_mfma_f32_16x16x32_bf16(qf[1], kb1, z, 0, 0, 0);
      sc[g] = z;
    }
    #pragma unroll
    for (int g = 0; g < 4; ++g) {
      float b = km[s0 + g*16 + l16] ? 0.f : -3e38f;
      #pragma unroll
      for (int r = 0; r < 4; ++r) sc[g][r] += b;
    }
    float mt[4];
    #pragma unroll
    for (int r = 0; r < 4; ++r) {
      float v = fmaxf(fmaxf(sc[0][r], sc[1][r]), fmaxf(sc[2][r], sc[3][r]));
      v = fmaxf(v, __shfl_xor(v, 1)); v = fmaxf(v, __shfl_xor(v, 2));
      v = fmaxf(v, __shfl_xor(v, 4)); v = fmaxf(v, __shfl_xor(v, 8));
      mt[r] = v;
    }
    float alpha[4];
    #pragma unroll
    for (int r = 0; r < 4; ++r) {
      float mn = fmaxf(m_run[r], mt[r]);
      alpha[r] = __builtin_amdgcn_exp2f((m_run[r] - mn) * LOG2E);
      m_run[r] = mn;
    }
    float rsum[4] = {0.f, 0.f, 0.f, 0.f};
    short pb[4][4];
    #pragma unroll
    for (int g = 0; g < 4; ++g)
      #pragma unroll
      for (int r = 0; r < 4; ++r) {
        float p = __builtin_amdgcn_exp2f((sc[g][r] - m_run[r]) * LOG2E);
        short s = f2bf(p); pb[g][r] = s; rsum[r] += bf2f(s);
      }
    #pragma unroll
    for (int r = 0; r < 4; ++r) {
      float v = rsum[r];
      v += __shfl_xor(v, 1); v += __shfl_xor(v, 2);
      v += __shfl_xor(v, 4); v += __shfl_xor(v, 8);
      l_run[r] = l_run[r] * alpha[r] + v;
    }
    #pragma unroll
    for (int g = 0; g < 4; ++g)
      #pragma unroll
      for (int r = 0; r < 4; ++r) o[g][r] *= alpha[r];
    short* pwf = pls[wid];
    #pragma unroll
    for (int g = 0; g < 4; ++g)
      #pragma unroll
      for (int r = 0; r < 4; ++r)
        pwf[(lg*4 + r) * RS + g*16 + l16] = pb[g][r];
    __syncthreads();
    bf16x8 pa0 = *(const bf16x8*)&pwf[l16 * RS + lg * 8];
    bf16x8 pa1 = *(const bf16x8*)&pwf[l16 * RS + 32 + lg * 8];
    #pragma unroll
    for (int gd = 0; gd < 4; ++gd) {
      bf16x8 vb0 = *(const bf16x8*)&vts[(gd*16 + l16) * RS + lg * 8];
      bf16x8 vb1 = *(const bf16x8*)&vts[(gd*16 + l16) * RS + 32 + lg * 8];
      o[gd] = __builtin_amdgcn_mfma_f32_16x16x32_bf16(pa0, vb0, o[gd], 0, 0, 0);
      o[gd] = __builtin_amdgcn_mfma_f32_16x16x32_bf16(pa1, vb1, o[gd], 0, 0, 0);
    }
  }
  float* op = Out + ((size_t)n * L_Q + q0) * HD + h * D_H;
  float inv[4];
  #pragma unroll
  for (int r = 0; r < 4; ++r) inv[r] = 1.0f / l_run[r];
  #pragma unroll
  for (int gd = 0; gd < 4; ++gd)
    #pragma unroll
    for (int r = 0; r < 4; ++r)
      op[(size_t)(lg*4 + r) * HD + gd*16 + l16] = o[gd][r] * inv[r];
}

extern "C" void kernel_launch(void* const* d_in, const int* in_sizes, int n_in,
                              void* d_out, int out_size, void* d_ws, size_t ws_size,
                              hipStream_t stream) {
  const float* Q = (const float*)d_in[0];
  const float* K = (const float*)d_in[1];
  const float* V = (const float*)d_in[2];
  const int* qm = (const int*)d_in[3];
  const int* km = (const int*)d_in[4];
  float* Out = (float*)d_out;
  (void)in_sizes; (void)n_in; (void)out_size;

  const size_t kbytes  = (size_t)N_B * S_K * HD * 2;   // 4 MiB each for K, V^T
  const size_t base_ml = 2 * kbytes + 1024;            // + mask bitfield
  const size_t mlb     = (size_t)NSP * PQT * sizeof(float);   // Mw / Lw
  const size_t owbb    = (size_t)NSP * PQT * D_H * 2;         // bf16 partials
  const size_t need    = base_ml + 2 * mlb + owbb;            // ~21.8 MB

  if (ws_size >= need) {
    short* kws  = (short*)d_ws;
    short* vtws = (short*)((char*)d_ws + kbytes);
    unsigned long long* mws = (unsigned long long*)((char*)d_ws + 2 * kbytes);
    float* Mw  = (float*)((char*)d_ws + base_ml);
    float* Lw  = Mw + NSP * PQT;
    short* Owb = (short*)(Lw + NSP * PQT);
    hipLaunchKernelGGL(preconv_kernel, dim3(1024), dim3(256), 0, stream,
                       K, V, km, kws, vtws, mws);
    hipLaunchKernelGGL(attn_fwd32, dim3(768), dim3(256), 0, stream,
                       Q, kws, vtws, mws, Owb, Mw, Lw);
    hipLaunchKernelGGL(combine_kernel, dim3(2048), dim3(256), 0, stream,
                       Owb, Mw, Lw, Out);
  } else {
    hipLaunchKernelGGL(attn_fwd_kernel, dim3(512), dim3(256), 0, stream,
                       Q, K, V, qm, km, Out);
  }
}